// Round 15
// baseline (55.653 us; speedup 1.0000x reference)
//
#include <hip/hip_runtime.h>

#define WINDOW 48
#define RES 50
#define PRED 96
#define BATCH 2048
#define KTOT 4800
#define KPAD 5120
#define KTRUNC 12
#define KS 20
#define KRB 256       // k per wave (one split) = 8 steps of 32

typedef __attribute__((ext_vector_type(8))) short short8v;   // 8 bf16
typedef __attribute__((ext_vector_type(4))) float f32x4;
typedef __attribute__((ext_vector_type(4))) int i32x4;

// ws float offsets
#define OFF_DK 0          // Dk[16][50]            800
#define OFF_WT 800        // Wt[50][96]            4800 -> 5600
#define OFF_KB 5600       // ushort Kb[64][5120]   163840 floats -> 169440
#define OFF_LP 169440     // Lp[20][2048][50]      2048000 -> 2217440 floats (8.9 MB)

__device__ __forceinline__ float ipow(float b, int n) {
    float r = 1.f, p = b;
    while (n) { if (n & 1) r *= p; p *= p; n >>= 1; }
    return r;
}

// RNE pack of two f32 into one u32 of 2 bf16 (pure 32-bit ops)
__device__ __forceinline__ unsigned pack2bf(float v0, float v1) {
    unsigned u0 = __builtin_bit_cast(unsigned, v0);
    unsigned u1 = __builtin_bit_cast(unsigned, v1);
    unsigned t0 = u0 + 0x7FFFu + ((u0 >> 16) & 1u);
    unsigned t1 = u1 + 0x7FFFu + ((u1 >> 16) & 1u);
    return (t0 >> 16) | (t1 & 0xFFFF0000u);
}

// k0: Dk + Wt (blocks 0-21) ; M into LDS (all blocks) ; Kb slice per block.
__global__ __launch_bounds__(256) void k0(const float* __restrict__ W_lin,
                                          const float* __restrict__ W_in,
                                          const float* __restrict__ d,
                                          const float* __restrict__ W_out,
                                          float* __restrict__ ws) {
    __shared__ float Ml[RES * WINDOW];
    int t = threadIdx.x, bid = blockIdx.x;
    int f = bid * 256 + t;
    if (f < 800) {                        // Dk[k][r] = d_r^(100k)
        int k = f / RES, r = f % RES;
        ws[OFF_DK + f] = ipow(ipow(d[r], 100), k);
    } else if (f < 5600) {                // Wt[r][o] = W_out[o][r]
        int e = f - 800;
        int r = e / PRED, o = e % PRED;
        ws[OFF_WT + e] = W_out[o * RES + r];
    }
    // M in LDS (each block computes all of M; 2400 dots)
    for (int e = t; e < RES * WINDOW; e += 256) {
        int c = e / WINDOW, w = e - c * WINDOW;
        float acc = 0.f;
        for (int v = 0; v < WINDOW; ++v)
            acc = fmaf(W_in[c * WINDOW + v], W_lin[v * WINDOW + w], acc);
        Ml[e] = acc;
    }
    __syncthreads();
    // Kb slice: entries [bid*2560, bid*2560+2560)
    unsigned short* Kb = (unsigned short*)(ws + OFF_KB);
    unsigned base = bid * 2560u;
#pragma unroll
    for (int i = 0; i < 10; ++i) {
        unsigned e = base + t + i * 256;
        int c = e / KPAD, k = e - (e / KPAD) * KPAD;
        float val = 0.f;
        if (c < RES && k < KTOT) {
            int j = k / WINDOW, w = k - j * WINDOW;
            val = ipow(d[c], 99 - j) * Ml[c * WINDOW + w];
        }
        unsigned u = __builtin_bit_cast(unsigned, val);
        Kb[e] = (unsigned short)((u + 0x7FFFu + ((u >> 16) & 1u)) >> 16);
    }
}

#define LOADA(st, A0, A1) {                                                   \
    const float* p_ = (kw + (st) * 32 < KTOT) ? (ap + (st) * 32) : x;         \
    A0 = *(const f32x4*)p_;  A1 = *(const f32x4*)(p_ + 4); }
#define LOADB(st, B0, B1, B2, B3) {                                           \
    const unsigned short* p_ = bp + (st) * 32;                                \
    B0 = *(const short8v*)p_;                B1 = *(const short8v*)(p_ + 16 * KPAD); \
    B2 = *(const short8v*)(p_ + 32 * KPAD);  B3 = *(const short8v*)(p_ + 48 * KPAD); }
#define COMPUTE(A0, A1, B0, B1, B2, B3) {                                     \
    i32x4 wv;                                                                 \
    wv[0] = (int)pack2bf(A0[0], A0[1]);                                       \
    wv[1] = (int)pack2bf(A0[2], A0[3]);                                       \
    wv[2] = (int)pack2bf(A1[0], A1[1]);                                       \
    wv[3] = (int)pack2bf(A1[2], A1[3]);                                       \
    short8v av = __builtin_bit_cast(short8v, wv);                             \
    acc0 = __builtin_amdgcn_mfma_f32_16x16x32_bf16(av, B0, acc0, 0, 0, 0);    \
    acc1 = __builtin_amdgcn_mfma_f32_16x16x32_bf16(av, B1, acc1, 0, 0, 0);    \
    acc2 = __builtin_amdgcn_mfma_f32_16x16x32_bf16(av, B2, acc2, 0, 0, 0);    \
    acc3 = __builtin_amdgcn_mfma_f32_16x16x32_bf16(av, B3, acc3, 0, 0, 0); }

// Block = 4 waves; wave w handles split s = sg*4+w over the block's 16 rows.
// 8 steps of 32 k, depth-3 static pipeline, single-bf16 A (no hi/lo split).
__global__ __launch_bounds__(256, 3) void k1(const float* __restrict__ x,
                                             const float* __restrict__ ws,
                                             float* __restrict__ lp) {
    const unsigned short* Kb = (const unsigned short*)(ws + OFF_KB);
    int bid = blockIdx.x;                 // 128 mt x 5 sg
    int mt = bid / 5, sg = bid - mt * 5;
    int t = threadIdx.x, w = t >> 6, l = t & 63;
    int s = sg * 4 + w;
    int b0 = mt * 16;
    int row16 = l & 15, kq = l >> 4;
    int kw = s * KRB + kq * 8;

    const float* ap = x + (size_t)(b0 + row16) * KTOT + kw;
    const unsigned short* bp = Kb + (size_t)row16 * KPAD + kw;

    f32x4 acc0 = (f32x4)(0.f), acc1 = (f32x4)(0.f), acc2 = (f32x4)(0.f), acc3 = (f32x4)(0.f);

    f32x4 a0p, a1p, a0q, a1q, a0r, a1r;
    short8v b0p, b1p, b2p, b3p, b0q, b1q, b2q, b3q, b0r, b1r, b2r, b3r;

    LOADA(0, a0p, a1p) LOADB(0, b0p, b1p, b2p, b3p)
    LOADA(1, a0q, a1q) LOADB(1, b0q, b1q, b2q, b3q)
    LOADA(2, a0r, a1r) LOADB(2, b0r, b1r, b2r, b3r)

    COMPUTE(a0p, a1p, b0p, b1p, b2p, b3p)  LOADA(3, a0p, a1p) LOADB(3, b0p, b1p, b2p, b3p)
    COMPUTE(a0q, a1q, b0q, b1q, b2q, b3q)  LOADA(4, a0q, a1q) LOADB(4, b0q, b1q, b2q, b3q)
    COMPUTE(a0r, a1r, b0r, b1r, b2r, b3r)  LOADA(5, a0r, a1r) LOADB(5, b0r, b1r, b2r, b3r)
    COMPUTE(a0p, a1p, b0p, b1p, b2p, b3p)  LOADA(6, a0p, a1p) LOADB(6, b0p, b1p, b2p, b3p)
    COMPUTE(a0q, a1q, b0q, b1q, b2q, b3q)  LOADA(7, a0q, a1q) LOADB(7, b0q, b1q, b2q, b3q)
    COMPUTE(a0r, a1r, b0r, b1r, b2r, b3r)
    COMPUTE(a0p, a1p, b0p, b1p, b2p, b3p)
    COMPUTE(a0q, a1q, b0q, b1q, b2q, b3q)

    float* dst = lp + ((size_t)s * BATCH + b0) * 50;
#pragma unroll
    for (int i = 0; i < 4; ++i) {
        int r = kq * 4 + i;
        dst[(size_t)r * 50 + row16]      = acc0[i];
        dst[(size_t)r * 50 + row16 + 16] = acc1[i];
        dst[(size_t)r * 50 + row16 + 32] = acc2[i];
        if (row16 < 2) dst[(size_t)r * 50 + row16 + 48] = acc3[i];
    }
}

// Fused: L-sum over splits (rows B0-11..B0+15) -> Dk-Horner -> W_out GEMM.
__global__ __launch_bounds__(256) void k2(const float* __restrict__ ws,
                                          float* __restrict__ out) {
    __shared__ float Ls[27 * 52];
    __shared__ float Ss[16 * 52];
    const float* lp = ws + OFF_LP;
    const float* Dk = ws + OFF_DK;
    const float* Wt = ws + OFF_WT;
    int B0 = blockIdx.x * 16;
    int t = threadIdx.x;

    for (int e = t; e < 27 * 50; e += 256) {
        int lr = e / 50, c = e - lr * 50;
        int bb = B0 - 11 + lr;
        float sum = 0.f;
        if (bb >= 0) {
#pragma unroll
            for (int sp = 0; sp < KS; ++sp)
                sum += lp[((size_t)sp * BATCH + bb) * 50 + c];
        }
        Ls[lr * 52 + c] = sum;
    }
    __syncthreads();

    for (int e = t; e < 16 * 50; e += 256) {
        int i = e / 50, r = e - i * 50;
        float acc = 0.f;
#pragma unroll
        for (int k = 0; k < KTRUNC; ++k)
            acc = fmaf(Dk[k * RES + r], Ls[(11 + i - k) * 52 + r], acc);
        Ss[i * 52 + r] = acc;
    }
    __syncthreads();

    for (int e = t; e < 16 * PRED; e += 256) {
        int i = e / PRED, o = e - i * PRED;
        float acc = 0.f;
#pragma unroll 10
        for (int r = 0; r < RES; ++r)
            acc = fmaf(Ss[i * 52 + r], Wt[r * PRED + o], acc);
        out[(B0 + i) * PRED + o] = acc;
    }
}

extern "C" void kernel_launch(void* const* d_in, const int* in_sizes, int n_in,
                              void* d_out, int out_size, void* d_ws, size_t ws_size,
                              hipStream_t stream) {
    const float* x     = (const float*)d_in[0];
    const float* W_lin = (const float*)d_in[1];
    const float* W_in  = (const float*)d_in[2];
    const float* d     = (const float*)d_in[3];
    const float* W_out = (const float*)d_in[4];
    float* out = (float*)d_out;
    float* ws  = (float*)d_ws;
    float* lp  = ws + OFF_LP;

    k0<<<128, 256, 0, stream>>>(W_lin, W_in, d, W_out, ws);
    k1<<<640, 256, 0, stream>>>(x, ws, lp);
    k2<<<128, 256, 0, stream>>>(ws, out);
}

// Round 16
// 36.011 us; speedup vs baseline: 1.5454x; 1.5454x over previous
//
#include <hip/hip_runtime.h>

#define WINDOW 48
#define RES 50
#define PRED 96
#define BATCH 2048
#define KTOT 4800
#define KTRUNC 12
#define KS 10
#define KRB 512       // k per block; wave w takes [w*128, w*128+128) = 4 steps of 32
#define ASTR 516      // LDS A row stride (floats): 16B-aligned, 2-way banks

typedef __attribute__((ext_vector_type(8))) short short8v;   // 8 bf16
typedef __attribute__((ext_vector_type(4))) float f32x4;
typedef __attribute__((ext_vector_type(4))) int i32x4;

// ws float offsets
#define OFF_DK 0          // Dk[16][50]                 800
#define OFF_WT 800        // Wt[50][96]                 4800 -> 5600
#define OFF_M  5600       // M[50][48]                  2400 -> 8000
#define OFF_KS 8000       // ushort KbSw[160][4][64][8] 327680 ushorts = 163840 fl -> 171840
#define OFF_LP 171840     // Lp[10][2048][50]           1024000 -> 1195840 floats (4.8 MB)

__device__ __forceinline__ float ipow(float b, int n) {
    float r = 1.f, p = b;
    while (n) { if (n & 1) r *= p; p *= p; n >>= 1; }
    return r;
}

// RNE pack of two f32 into one u32 of 2 bf16 (pure 32-bit ops)
__device__ __forceinline__ unsigned pack2bf(float v0, float v1) {
    unsigned u0 = __builtin_bit_cast(unsigned, v0);
    unsigned u1 = __builtin_bit_cast(unsigned, v1);
    unsigned t0 = u0 + 0x7FFFu + ((u0 >> 16) & 1u);
    unsigned t1 = u1 + 0x7FFFu + ((u1 >> 16) & 1u);
    return (t0 >> 16) | (t1 & 0xFFFF0000u);
}

// k0a: M[r][w], Dk[k][r], Wt[r][o]
__global__ __launch_bounds__(256) void k0a(const float* __restrict__ W_lin,
                                           const float* __restrict__ W_in,
                                           const float* __restrict__ d,
                                           const float* __restrict__ W_out,
                                           float* __restrict__ ws) {
    int f = blockIdx.x * 256 + threadIdx.x;
    if (f < 2400) {
        int r = f / WINDOW, w = f % WINDOW;
        float acc = 0.f;
        for (int v = 0; v < WINDOW; ++v)
            acc = fmaf(W_in[r * WINDOW + v], W_lin[v * WINDOW + w], acc);
        ws[OFF_M + f] = acc;
    } else if (f < 3200) {
        int e = f - 2400;                 // Dk[k][r] = d_r^(100k)
        int k = e / RES, r = e % RES;
        ws[OFF_DK + e] = ipow(ipow(d[r], 100), k);
    } else if (f < 8000) {
        int e = f - 3200;                 // Wt[r][o] = W_out[o][r]
        int r = e / PRED, o = e % PRED;
        ws[OFF_WT + e] = W_out[o * RES + r];
    }
}

// k0b: KbSw in FRAGMENT ORDER. idx = ((K*4+n)*64 + l)*8 + j holds
// bf16( d_c^(99 - k/48) * M[c][k%48] ) with c = 16n + (l&15), k = 32K + (l>>4)*8 + j.
// Consuming wave reads base + l*16 -> dense 1KB per instruction.
__global__ __launch_bounds__(256) void k0b(const float* __restrict__ d,
                                           float* __restrict__ ws) {
    unsigned idx = blockIdx.x * 256 + threadIdx.x;   // < 327680
    int j = idx & 7;
    int l = (idx >> 3) & 63;
    int n = (idx >> 9) & 3;
    int K = idx >> 11;                   // 0..159
    int c = n * 16 + (l & 15);
    int k = K * 32 + ((l >> 4) << 3) + j;
    float val = 0.f;
    if (c < RES && k < KTOT) {
        int jj = k / WINDOW, w = k - jj * WINDOW;
        val = ipow(d[c], 99 - jj) * ws[OFF_M + c * WINDOW + w];
    }
    unsigned u = __builtin_bit_cast(unsigned, val);
    ((unsigned short*)(ws + OFF_KS))[idx] =
        (unsigned short)((u + 0x7FFFu + ((u >> 16) & 1u)) >> 16);
}

// Block = 4 waves, 16 rows x 512 k. A staged dense in LDS; B dense from KbSw.
// Per wave: 4 steps x (2 ds_read_b128 + 4 pack + 4 dense B + 4 MFMA).
// Cross-wave reduce via re-aliased LDS -> Lp[ks][b][c] (50 cols).
__global__ __launch_bounds__(256, 3) void k1(const float* __restrict__ x,
                                             const float* __restrict__ ws,
                                             float* __restrict__ lp) {
    __shared__ float S[16 * ASTR];        // 33 KB; aliased as Ps[4][16][68] later
    const unsigned short* KbSw = (const unsigned short*)(ws + OFF_KS);
    int bid = blockIdx.x;                 // 128 mt x 10 ks
    int mt = bid / KS, ks = bid - mt * KS;
    int b0 = mt * 16, kb = ks * KRB;
    int t = threadIdx.x, w = t >> 6, l = t & 63;
    int row16 = l & 15, kq = l >> 4;

    // --- stage A panel: dense float4 (1KB per wave-instr), zero-pad k>=4800 ---
#pragma unroll
    for (int i = 0; i < 8; ++i) {
        int e = t + i * 256;              // < 2048 float4s
        int row = e >> 7, q = e & 127;
        float4 v = make_float4(0.f, 0.f, 0.f, 0.f);
        if (kb + 4 * q < KTOT)
            v = *(const float4*)(x + (size_t)(b0 + row) * KTOT + kb + 4 * q);
        *(float4*)(S + row * ASTR + 4 * q) = v;
    }
    __syncthreads();

    // --- hoist all 16 dense B loads (64 VGPR) ---
    int K0 = ks * 16 + w * 4;             // global 32k-step base for this wave
    const unsigned short* bbase = KbSw + (size_t)K0 * 2048 + l * 8;
    short8v B0[4], B1[4], B2[4], B3[4];
#pragma unroll
    for (int st = 0; st < 4; ++st) {
        B0[st] = *(const short8v*)(bbase + st * 2048);
        B1[st] = *(const short8v*)(bbase + st * 2048 + 512);
        B2[st] = *(const short8v*)(bbase + st * 2048 + 1024);
        B3[st] = *(const short8v*)(bbase + st * 2048 + 1536);
    }

    f32x4 acc0 = (f32x4)(0.f), acc1 = (f32x4)(0.f), acc2 = (f32x4)(0.f), acc3 = (f32x4)(0.f);
    const float* abase = S + row16 * ASTR + w * 128 + kq * 8;

#pragma unroll
    for (int st = 0; st < 4; ++st) {
        f32x4 a0 = *(const f32x4*)(abase + st * 32);
        f32x4 a1 = *(const f32x4*)(abase + st * 32 + 4);
        i32x4 wv;
        wv[0] = (int)pack2bf(a0[0], a0[1]);
        wv[1] = (int)pack2bf(a0[2], a0[3]);
        wv[2] = (int)pack2bf(a1[0], a1[1]);
        wv[3] = (int)pack2bf(a1[2], a1[3]);
        short8v av = __builtin_bit_cast(short8v, wv);
        acc0 = __builtin_amdgcn_mfma_f32_16x16x32_bf16(av, B0[st], acc0, 0, 0, 0);
        acc1 = __builtin_amdgcn_mfma_f32_16x16x32_bf16(av, B1[st], acc1, 0, 0, 0);
        acc2 = __builtin_amdgcn_mfma_f32_16x16x32_bf16(av, B2[st], acc2, 0, 0, 0);
        acc3 = __builtin_amdgcn_mfma_f32_16x16x32_bf16(av, B3[st], acc3, 0, 0, 0);
    }
    __syncthreads();                      // all A ds_reads done -> alias S as Ps

    float* Ps = S + w * 1088;             // [16][68] per wave
#pragma unroll
    for (int i = 0; i < 4; ++i) {
        int rr = (kq * 4 + i) * 68;
        Ps[rr + row16]      = acc0[i];
        Ps[rr + row16 + 16] = acc1[i];
        Ps[rr + row16 + 32] = acc2[i];
        Ps[rr + row16 + 48] = acc3[i];
    }
    __syncthreads();

#pragma unroll
    for (int i = 0; i < 4; ++i) {
        int o = t + i * 256;              // < 1024
        int r = o >> 6, c = o & 63;
        if (c < RES) {
            float sum = (S[r * 68 + c] + S[1088 + r * 68 + c])
                      + (S[2176 + r * 68 + c] + S[3264 + r * 68 + c]);
            lp[((size_t)ks * BATCH + b0 + r) * 50 + c] = sum;
        }
    }
}

// Fused: L-sum over splits (rows B0-11..B0+15) -> Dk-Horner -> W_out GEMM.
__global__ __launch_bounds__(256) void k2(const float* __restrict__ ws,
                                          float* __restrict__ out) {
    __shared__ float Ls[27 * 52];
    __shared__ float Ss[16 * 52];
    const float* lp = ws + OFF_LP;
    const float* Dk = ws + OFF_DK;
    const float* Wt = ws + OFF_WT;
    int B0 = blockIdx.x * 16;
    int t = threadIdx.x;

    for (int e = t; e < 27 * 50; e += 256) {
        int lr = e / 50, c = e - lr * 50;
        int bb = B0 - 11 + lr;
        float sum = 0.f;
        if (bb >= 0) {
#pragma unroll
            for (int sp = 0; sp < KS; ++sp)
                sum += lp[((size_t)sp * BATCH + bb) * 50 + c];
        }
        Ls[lr * 52 + c] = sum;
    }
    __syncthreads();

    for (int e = t; e < 16 * 50; e += 256) {
        int i = e / 50, r = e - i * 50;
        float acc = 0.f;
#pragma unroll
        for (int k = 0; k < KTRUNC; ++k)
            acc = fmaf(Dk[k * RES + r], Ls[(11 + i - k) * 52 + r], acc);
        Ss[i * 52 + r] = acc;
    }
    __syncthreads();

    for (int e = t; e < 16 * PRED; e += 256) {
        int i = e / PRED, o = e - i * PRED;
        float acc = 0.f;
#pragma unroll 10
        for (int r = 0; r < RES; ++r)
            acc = fmaf(Ss[i * 52 + r], Wt[r * PRED + o], acc);
        out[(B0 + i) * PRED + o] = acc;
    }
}

extern "C" void kernel_launch(void* const* d_in, const int* in_sizes, int n_in,
                              void* d_out, int out_size, void* d_ws, size_t ws_size,
                              hipStream_t stream) {
    const float* x     = (const float*)d_in[0];
    const float* W_lin = (const float*)d_in[1];
    const float* W_in  = (const float*)d_in[2];
    const float* d     = (const float*)d_in[3];
    const float* W_out = (const float*)d_in[4];
    float* out = (float*)d_out;
    float* ws  = (float*)d_ws;
    float* lp  = ws + OFF_LP;

    k0a<<<32, 256, 0, stream>>>(W_lin, W_in, d, W_out, ws);
    k0b<<<1280, 256, 0, stream>>>(d, ws);
    k1<<<128 * KS, 256, 0, stream>>>(x, ws, lp);
    k2<<<128, 256, 0, stream>>>(ws, out);
}